// Round 13
// baseline (285.567 us; speedup 1.0000x reference)
//
#include <hip/hip_runtime.h>
#include <hip/hip_bf16.h>
#include <math.h>

#define IN_DIM  128
#define HID     64
#define H1      4
#define H2      2
#define OUT_DIM 64
#define D1      256   // H1*HID
#define D2      128   // H2*OUT_DIM
#define LRELU   0.2f
#define LN_EPS  1e-5f
#define BK      16    // nodes per fill bucket
#define NSS     64    // stripes; stripe = (e>>8)&63 = scatter blockIdx mod 64
#define MAXNB   4096  // LDS histogram capacity (NB=3125 here)

using short8 = __attribute__((ext_vector_type(8))) short;
using f32x4  = __attribute__((ext_vector_type(4))) float;

static __device__ __forceinline__ unsigned short f2bf_bits(float f)
{
    __hip_bfloat16 b = __float2bfloat16(f);
    return *reinterpret_cast<unsigned short*>(&b);
}
static __device__ __forceinline__ float2 unpack_bf2(unsigned int p)
{
    float2 r;
    r.x = __uint_as_float(p << 16);
    r.y = __uint_as_float(p & 0xffff0000u);
    return r;
}
static __device__ __forceinline__ unsigned int pack_bf2(float x, float y)
{
    return (unsigned int)f2bf_bits(x) | ((unsigned int)f2bf_bits(y) << 16);
}

static __device__ __forceinline__ float lrelu_exp(float v)
{
    v = v > 0.f ? v : LRELU * v;
    return __expf(v);
}

// inline int64-vs-int32 edge_index probe: int64 data has zero odd words.
static __device__ __forceinline__ int detect_i64(const int* __restrict__ ei)
{
    int any_odd_nonzero = 0;
    #pragma unroll
    for (int k = 1; k < 16; k += 2) any_odd_nonzero |= (ei[k] != 0);
    return any_odd_nonzero ? 0 : 1;
}

// ---------------- fused weight pre-pack + single-owner stripe histograms ----------------
// blocks [0,256): pack W1/W2. blocks [256,256+NSS): block s owns edge-groups
// g == s (mod 64); LDS histogram of 16-node buckets, then PLAIN STORE to
// sdeg[s*NB+b] — no global atomics, no zero-init needed.
__global__ __launch_bounds__(256) void conv_hist_kernel(
    const float* __restrict__ W1, const float* __restrict__ W2,
    unsigned short* __restrict__ Wp1, unsigned short* __restrict__ Wp2,
    const int* __restrict__ ei, int E, int* __restrict__ sdeg, int NB)
{
    __shared__ int hist[MAXNB];
    const int bid = blockIdx.x;
    if (bid < 256) {
        int tid = bid * 256 + threadIdx.x;   // 0..65535
        if (tid < 32768) {                   // W1: 4 ksteps x 16 stripes
            int j = tid & 7, l = (tid >> 3) & 63, rest = tid >> 9;
            int s = rest & 15, t = rest >> 4;
            int k = t * 32 + (l >> 4) * 8 + j, col = s * 16 + (l & 15);
            Wp1[tid] = f2bf_bits(W1[k * D1 + col]);
        } else {                             // W2: 8 ksteps x 8 stripes
            int id = tid - 32768;
            int j = id & 7, l = (id >> 3) & 63, rest = id >> 9;
            int s = rest & 7, t = rest >> 3;
            int k = t * 32 + (l >> 4) * 8 + j, col = s * 16 + (l & 15);
            Wp2[id] = f2bf_bits(W2[k * D2 + col]);
        }
        return;
    }

    const int i64f = detect_i64(ei);
    const int s = bid - 256;                 // stripe in [0,64)
    const int numGroups = (E + 255) >> 8;

    for (int i = threadIdx.x; i < NB; i += 256) hist[i] = 0;
    __syncthreads();

    for (int g = s; g < numGroups; g += NSS) {
        int e = (g << 8) + threadIdx.x;
        if (e < E) {
            int dst = i64f ? ei[2 * ((size_t)E + e)] : ei[E + e];
            atomicAdd(&hist[dst >> 4], 1);   // BK=16 (LDS atomic)
        }
    }
    __syncthreads();
    for (int i = threadIdx.x; i < NB; i += 256)
        sdeg[s * NB + i] = hist[i];          // single owner: plain store
}

// ---------------- fused scan_partial(sdeg, (b,s)-order) + MFMA GEMM1 ----------------
__global__ __launch_bounds__(256) void scan_gemm1_kernel(
    const int* __restrict__ sdeg, int NB, int M, int* __restrict__ bsum, int scanB,
    const float* __restrict__ x, const unsigned short* __restrict__ Wp,
    const float* __restrict__ att_s, const float* __restrict__ att_d,
    unsigned short* __restrict__ h1b,
    float* __restrict__ al_s, float* __restrict__ al_d, int N)
{
    __shared__ __align__(16) unsigned short As[16 * 136];  // K=128 pad->136
    const int tid = threadIdx.x;

    if ((int)blockIdx.x < scanB) {
        int* sh = (int*)As;   // reuse LDS
        int i = blockIdx.x * 256 + tid;
        int v = 0;
        if (i < M) v = sdeg[(i & 63) * NB + (i >> 6)];   // (b,s) lexicographic
        sh[tid] = v;
        __syncthreads();
        for (int st = 128; st > 0; st >>= 1) {
            if (tid < st) sh[tid] += sh[tid + st];
            __syncthreads();
        }
        if (tid == 0) bsum[blockIdx.x] = sh[0];
        return;
    }

    const int n0 = ((int)blockIdx.x - scanB) * 16;
    const int l = tid & 63, w = tid >> 6;

    #pragma unroll
    for (int it = 0; it < 2; ++it) {
        int ch = tid + it * 256;            // 512 chunks of 4 floats
        int r = ch >> 5, c4 = (ch & 31) * 4;
        int row = n0 + r;
        float4 v = (row < N) ? ((const float4*)x)[(size_t)row * 32 + (c4 >> 2)]
                             : make_float4(0.f, 0.f, 0.f, 0.f);
        ushort4 pk = make_ushort4(f2bf_bits(v.x), f2bf_bits(v.y),
                                  f2bf_bits(v.z), f2bf_bits(v.w));
        *(ushort4*)&As[r * 136 + c4] = pk;
    }

    short8 bfr[4][4];
    #pragma unroll
    for (int t = 0; t < 4; ++t)
        #pragma unroll
        for (int p = 0; p < 4; ++p)
            bfr[t][p] = ((const short8*)Wp)[(t * 16 + (w * 4 + p)) * 64 + l];

    __syncthreads();

    f32x4 acc[4] = {{0.f,0.f,0.f,0.f},{0.f,0.f,0.f,0.f},
                    {0.f,0.f,0.f,0.f},{0.f,0.f,0.f,0.f}};
    #pragma unroll
    for (int t = 0; t < 4; ++t) {
        short8 a = *(const short8*)&As[(l & 15) * 136 + t * 32 + (l >> 4) * 8];
        #pragma unroll
        for (int p = 0; p < 4; ++p)
            acc[p] = __builtin_amdgcn_mfma_f32_16x16x32_bf16(a, bfr[t][p], acc[p], 0, 0, 0);
    }

    const int colbase = w * 64 + (l & 15);
    const int rowbase = n0 + (l >> 4) * 4;
    #pragma unroll
    for (int p = 0; p < 4; ++p) {
        int col = colbase + p * 16;
        #pragma unroll
        for (int r = 0; r < 4; ++r) {
            int row = rowbase + r;
            if (row < N) h1b[(size_t)row * D1 + col] = f2bf_bits(acc[p][r]);
        }
    }

    float as_p[4], ad_p[4];
    #pragma unroll
    for (int p = 0; p < 4; ++p) {
        as_p[p] = att_s[colbase + p * 16];
        ad_p[p] = att_d[colbase + p * 16];
    }
    #pragma unroll
    for (int r = 0; r < 4; ++r) {
        float ps = acc[0][r] * as_p[0] + acc[1][r] * as_p[1]
                 + acc[2][r] * as_p[2] + acc[3][r] * as_p[3];
        float pd = acc[0][r] * ad_p[0] + acc[1][r] * ad_p[1]
                 + acc[2][r] * ad_p[2] + acc[3][r] * ad_p[3];
        #pragma unroll
        for (int off = 8; off > 0; off >>= 1) {
            ps += __shfl_down(ps, off);
            pd += __shfl_down(pd, off);
        }
        int row = rowbase + r;
        if ((l & 15) == 0 && row < N) {
            al_s[(size_t)row * H1 + w] = ps;
            al_d[(size_t)row * H1 + w] = pd;
        }
    }
}

// scan_final over M=NB*64 elements in (b,s) order. Block offset computed by
// strided reduction over bsum[0..blockIdx) (B can exceed 256).
__global__ __launch_bounds__(256) void scan_final(
    const int* __restrict__ sdeg, const int* __restrict__ bsum, int M, int NB,
    int* __restrict__ start, int* __restrict__ bcur)
{
    __shared__ int red[256];
    __shared__ int s[256];
    int part = 0;
    for (int j = threadIdx.x; j < (int)blockIdx.x; j += 256) part += bsum[j];
    red[threadIdx.x] = part;
    __syncthreads();
    for (int st = 128; st > 0; st >>= 1) {
        if (threadIdx.x < st) red[threadIdx.x] += red[threadIdx.x + st];
        __syncthreads();
    }
    const int blockOff = red[0];

    int i = blockIdx.x * 256 + threadIdx.x;
    int v = (i < M) ? sdeg[(i & 63) * NB + (i >> 6)] : 0;
    s[threadIdx.x] = v;
    __syncthreads();
    for (int st = 1; st < 256; st <<= 1) {
        int t = (threadIdx.x >= st) ? s[threadIdx.x - st] : 0;
        __syncthreads();
        s[threadIdx.x] += t;
        __syncthreads();
    }
    int excl = s[threadIdx.x] - v + blockOff;
    if (i < M) {
        start[i] = excl;                       // (b,s)-major, pristine
        bcur[(i & 63) * NB + (i >> 6)] = excl; // stripe-major cursors
    }
}

// ---------------- scatter edges into (bucket,stripe) regions ----------------
// stripe = (e>>8)&63 == blockIdx mod 64 -> cursor lines single-XCD-class;
// chains = E/(NB*64) ~ 4.
__global__ __launch_bounds__(256) void bucket_scatter(
    const int* __restrict__ ei, int E, int NB,
    int* __restrict__ bcur, unsigned int* __restrict__ pairs)
{
    const int i64f = detect_i64(ei);
    int e = blockIdx.x * 256 + threadIdx.x;
    if (e >= E) return;
    int src, dst;
    if (i64f) { src = ei[2 * (size_t)e]; dst = ei[2 * ((size_t)E + e)]; }
    else      { src = ei[e];             dst = ei[E + e]; }
    int s = (e >> 8) & 63;
    int pos = atomicAdd(&bcur[s * NB + (dst >> 4)], 1);
    pairs[pos] = ((unsigned int)src << 16) | (unsigned int)dst;
}

// ---------------- fill2: derive per-node offsets in LDS, write rowptr + csr ----------------
__global__ __launch_bounds__(256) void fill2_kernel(
    const unsigned int* __restrict__ pairs, const int* __restrict__ start,
    int N, int NB, int E,
    int* __restrict__ rowptr, int* __restrict__ csr_src)
{
    __shared__ int cnt[BK], cur[BK];
    __shared__ int stage[2048];
    const int b = blockIdx.x;
    const int t = threadIdx.x;
    const int base = start[b * NSS];
    const int segend = (b + 1 < NB) ? start[(b + 1) * NSS] : E;
    const int seglen = segend - base;

    if (t < BK) cnt[t] = 0;
    __syncthreads();
    for (int i = t; i < seglen; i += 256)
        atomicAdd(&cnt[pairs[base + i] & (BK - 1)], 1);
    __syncthreads();
    if (t == 0) {
        int run = 0;
        for (int j = 0; j < BK; ++j) {
            cur[j] = run;
            int node = b * BK + j;
            if (node < N) rowptr[node] = base + run;
            run += cnt[j];
        }
        if (b == NB - 1) rowptr[N] = E;
    }
    __syncthreads();

    if (seglen <= 2048) {
        for (int i = t; i < seglen; i += 256) {
            unsigned int p = pairs[base + i];
            int pos = atomicAdd(&cur[p & (BK - 1)], 1);
            stage[pos] = (int)(p >> 16);
        }
        __syncthreads();
        for (int i = t; i < seglen; i += 256)
            csr_src[base + i] = stage[i];
    } else {
        for (int i = t; i < seglen; i += 256) {
            unsigned int p = pairs[base + i];
            int pos = atomicAdd(&cur[p & (BK - 1)], 1);
            csr_src[base + pos] = (int)(p >> 16);
        }
    }
}

// ---------------- MFMA GEMM2: h2b[N,128] = hmidb[N,256] @ W2 + fused logits ----------------
__global__ __launch_bounds__(256) void gemm2_mfma(
    const unsigned short* __restrict__ hmidb, const unsigned short* __restrict__ Wp,
    const float* __restrict__ att_s, const float* __restrict__ att_d,
    unsigned short* __restrict__ h2b,
    float* __restrict__ al_s, float* __restrict__ al_d, int N)
{
    __shared__ __align__(16) unsigned short As[16 * 264];  // K=256 pad->264
    __shared__ float psL[4][16], pdL[4][16];
    const int tid = threadIdx.x;
    const int n0 = blockIdx.x * 16;
    const int l = tid & 63, w = tid >> 6;

    const short8 zero8 = {0,0,0,0,0,0,0,0};
    #pragma unroll
    for (int it = 0; it < 2; ++it) {
        int ch = tid + it * 256;            // 512 chunks of 8 bf16
        int r = ch >> 5, c8 = (ch & 31) * 8;
        int row = n0 + r;
        short8 v = (row < N) ? ((const short8*)hmidb)[(size_t)row * 32 + (ch & 31)] : zero8;
        *(short8*)&As[r * 264 + c8] = v;
    }

    short8 bfr[8][2];
    #pragma unroll
    for (int t = 0; t < 8; ++t)
        #pragma unroll
        for (int q = 0; q < 2; ++q)
            bfr[t][q] = ((const short8*)Wp)[(t * 8 + (w * 2 + q)) * 64 + l];

    __syncthreads();

    f32x4 acc[2] = {{0.f,0.f,0.f,0.f},{0.f,0.f,0.f,0.f}};
    #pragma unroll
    for (int t = 0; t < 8; ++t) {
        short8 a = *(const short8*)&As[(l & 15) * 264 + t * 32 + (l >> 4) * 8];
        #pragma unroll
        for (int q = 0; q < 2; ++q)
            acc[q] = __builtin_amdgcn_mfma_f32_16x16x32_bf16(a, bfr[t][q], acc[q], 0, 0, 0);
    }

    const int colbase = w * 32 + (l & 15);
    const int rowbase = n0 + (l >> 4) * 4;
    #pragma unroll
    for (int q = 0; q < 2; ++q) {
        int col = colbase + q * 16;
        #pragma unroll
        for (int r = 0; r < 4; ++r) {
            int row = rowbase + r;
            if (row < N) h2b[(size_t)row * D2 + col] = f2bf_bits(acc[q][r]);
        }
    }

    float as_q[2], ad_q[2];
    #pragma unroll
    for (int q = 0; q < 2; ++q) {
        as_q[q] = att_s[colbase + q * 16];
        ad_q[q] = att_d[colbase + q * 16];
    }
    #pragma unroll
    for (int r = 0; r < 4; ++r) {
        float ps = acc[0][r] * as_q[0] + acc[1][r] * as_q[1];
        float pd = acc[0][r] * ad_q[0] + acc[1][r] * ad_q[1];
        #pragma unroll
        for (int off = 8; off > 0; off >>= 1) {
            ps += __shfl_down(ps, off);
            pd += __shfl_down(pd, off);
        }
        if ((l & 15) == 0) {
            psL[w][(l >> 4) * 4 + r] = ps;
            pdL[w][(l >> 4) * 4 + r] = pd;
        }
    }
    __syncthreads();
    if (tid < 32) {
        int rl = tid & 15, hh = tid >> 4;
        int row = n0 + rl;
        if (row < N) {
            al_s[(size_t)row * H2 + hh] = psL[2*hh][rl] + psL[2*hh+1][rl];
            al_d[(size_t)row * H2 + hh] = pdL[2*hh][rl] + pdL[2*hh+1][rl];
        }
    }
}

// ---------------- Layer-1 aggregation: 64 thr/node, 4 ch/lane, 4-wide, loads-first ----------
__global__ __launch_bounds__(64) void agg1_kernel(
    const int* __restrict__ rowptr, const int* __restrict__ csr_src,
    const uint2* __restrict__ h1p,   // [N,64] packed bf16x4
    const float* __restrict__ al_s, const float* __restrict__ al_d,
    const float* __restrict__ b1,
    const float* __restrict__ ln_w, const float* __restrict__ ln_b,
    uint2* __restrict__ hmidp, int N)  // [N,64] packed bf16x4 out
{
    const int n = blockIdx.x;
    const int l = threadIdx.x;
    const int h = l >> 4;
    const float ad = al_d[(size_t)n * H1 + h];

    float a0[4] = {0.f,0.f,0.f,0.f}, a1[4] = {0.f,0.f,0.f,0.f};
    float a2[4] = {0.f,0.f,0.f,0.f}, a3[4] = {0.f,0.f,0.f,0.f};
    float dn0, dn1 = 0.f, dn2 = 0.f, dn3 = 0.f;

    {   // self loop
        float w = lrelu_exp(al_s[(size_t)n * H1 + h] + ad);
        uint2 p = h1p[(size_t)n * 64 + l];
        float2 va = unpack_bf2(p.x), vb = unpack_bf2(p.y);
        a0[0] = w * va.x; a0[1] = w * va.y; a0[2] = w * vb.x; a0[3] = w * vb.y;
        dn0 = w;
    }

    const int beg = rowptr[n], end = rowptr[n + 1];
    int i = beg;

#define LOADI(k)  int s##k = csr_src[i + k];
#define LOADR(k)  uint2 p##k = h1p[(size_t)s##k * 64 + l]; \
                  float g##k = al_s[(size_t)s##k * H1 + h];
#define WACC(A, D, k) { float w = lrelu_exp(g##k + ad); \
                        float2 va = unpack_bf2(p##k.x), vb = unpack_bf2(p##k.y); \
                        A[0] += w * va.x; A[1] += w * va.y; \
                        A[2] += w * vb.x; A[3] += w * vb.y; D += w; }

    for (; i + 4 <= end; i += 4) {
        LOADI(0) LOADI(1) LOADI(2) LOADI(3)
        LOADR(0) LOADR(1) LOADR(2) LOADR(3)
        WACC(a0, dn0, 0) WACC(a1, dn1, 1) WACC(a2, dn2, 2) WACC(a3, dn3, 3)
    }
    for (; i < end; ++i) {
        LOADI(0) LOADR(0) WACC(a0, dn0, 0)
    }
#undef LOADI
#undef LOADR
#undef WACC

    const float inv = 1.f / ((dn0 + dn1) + (dn2 + dn3));
    float4 bb = ((const float4*)b1)[l];
    float v[4];
    v[0] = ((a0[0]+a1[0]) + (a2[0]+a3[0])) * inv + bb.x;
    v[1] = ((a0[1]+a1[1]) + (a2[1]+a3[1])) * inv + bb.y;
    v[2] = ((a0[2]+a1[2]) + (a2[2]+a3[2])) * inv + bb.z;
    v[3] = ((a0[3]+a1[3]) + (a2[3]+a3[3])) * inv + bb.w;

    // LayerNorm over 256 channels: single-wave shfl reduction
    float s  = (v[0]+v[1]) + (v[2]+v[3]);
    float s2 = (v[0]*v[0]+v[1]*v[1]) + (v[2]*v[2]+v[3]*v[3]);
    #pragma unroll
    for (int off = 32; off > 0; off >>= 1) {
        s  += __shfl_down(s,  off);
        s2 += __shfl_down(s2, off);
    }
    const float mu   = __shfl(s,  0) * (1.f / 256.f);
    const float ex2  = __shfl(s2, 0) * (1.f / 256.f);
    const float rstd = rsqrtf(ex2 - mu * mu + LN_EPS);
    float4 lw = ((const float4*)ln_w)[l];
    float4 lb = ((const float4*)ln_b)[l];
    float y0 = (v[0] - mu) * rstd * lw.x + lb.x;
    float y1 = (v[1] - mu) * rstd * lw.y + lb.y;
    float y2 = (v[2] - mu) * rstd * lw.z + lb.z;
    float y3 = (v[3] - mu) * rstd * lw.w + lb.w;
    y0 = y0 > 0.f ? y0 : (__expf(y0) - 1.f);
    y1 = y1 > 0.f ? y1 : (__expf(y1) - 1.f);
    y2 = y2 > 0.f ? y2 : (__expf(y2) - 1.f);
    y3 = y3 > 0.f ? y3 : (__expf(y3) - 1.f);
    uint2 outp;
    outp.x = pack_bf2(y0, y1);
    outp.y = pack_bf2(y2, y3);
    hmidp[(size_t)n * 64 + l] = outp;
}

// ---------------- Layer-2 aggregation: 64 thr/node, 2 ch/lane, 4-wide + shfl head-mean ------
__global__ __launch_bounds__(64) void agg2_kernel(
    const int* __restrict__ rowptr, const int* __restrict__ csr_src,
    const unsigned int* __restrict__ h2p,   // [N,64] packed bf16x2
    const float* __restrict__ al_s, const float* __restrict__ al_d,
    const float* __restrict__ b2,
    float* __restrict__ out, int N)
{
    const int n = blockIdx.x;
    const int l = threadIdx.x;
    const int h = l >> 5;
    const float ad = al_d[(size_t)n * H2 + h];

    float ax0, ay0, dn0;
    float ax1 = 0.f, ay1 = 0.f, dn1 = 0.f;
    float ax2 = 0.f, ay2 = 0.f, dn2 = 0.f;
    float ax3 = 0.f, ay3 = 0.f, dn3 = 0.f;
    {
        float w = lrelu_exp(al_s[(size_t)n * H2 + h] + ad);
        float2 hv = unpack_bf2(h2p[(size_t)n * 64 + l]);
        ax0 = w * hv.x; ay0 = w * hv.y; dn0 = w;
    }

    const int beg = rowptr[n], end = rowptr[n + 1];
    int i = beg;

#define LOADI(k)  int s##k = csr_src[i + k];
#define LOADR(k)  unsigned int p##k = h2p[(size_t)s##k * 64 + l]; \
                  float g##k = al_s[(size_t)s##k * H2 + h];
#define WACC(AX, AY, D, k) { float w = lrelu_exp(g##k + ad); \
                             float2 vv = unpack_bf2(p##k); \
                             AX += w * vv.x; AY += w * vv.y; D += w; }

    for (; i + 4 <= end; i += 4) {
        LOADI(0) LOADI(1) LOADI(2) LOADI(3)
        LOADR(0) LOADR(1) LOADR(2) LOADR(3)
        WACC(ax0, ay0, dn0, 0) WACC(ax1, ay1, dn1, 1)
        WACC(ax2, ay2, dn2, 2) WACC(ax3, ay3, dn3, 3)
    }
    for (; i < end; ++i) {
        LOADI(0) LOADR(0) WACC(ax0, ay0, dn0, 0)
    }
#undef LOADI
#undef LOADR
#undef WACC

    const float inv = 1.f / ((dn0 + dn1) + (dn2 + dn3));
    const float vx = ((ax0 + ax1) + (ax2 + ax3)) * inv;
    const float vy = ((ay0 + ay1) + (ay2 + ay3)) * inv;

    // head mean via shfl: lane i<32 holds head0 ch {2i,2i+1}, lane 32+i head1.
    const float vx1 = __shfl(vx, l + 32);
    const float vy1 = __shfl(vy, l + 32);
    if (l < 32) {
        float2 bb = ((const float2*)b2)[l];
        float2 o;
        o.x = 0.5f * (vx + vx1) + bb.x;
        o.y = 0.5f * (vy + vy1) + bb.y;
        ((float2*)out)[(size_t)n * 32 + l] = o;
    }
}

extern "C" void kernel_launch(void* const* d_in, const int* in_sizes, int n_in,
                              void* d_out, int out_size, void* d_ws, size_t ws_size,
                              hipStream_t stream)
{
    const float* x   = (const float*)d_in[0];
    const int*   ei  = (const int*)d_in[1];
    const float* W1  = (const float*)d_in[2];
    const float* as1 = (const float*)d_in[3];
    const float* ad1 = (const float*)d_in[4];
    const float* b1  = (const float*)d_in[5];
    const float* lnw = (const float*)d_in[6];
    const float* lnb = (const float*)d_in[7];
    const float* W2  = (const float*)d_in[8];
    const float* as2 = (const float*)d_in[9];
    const float* ad2 = (const float*)d_in[10];
    const float* b2  = (const float*)d_in[11];

    const int N = in_sizes[0] / IN_DIM;   // 50000 (< 65536: uint16 packing valid)
    const int E = in_sizes[1] / 2;        // 800000
    const int NB = (N + BK - 1) / BK;     // 3125 buckets (<= MAXNB)
    const int M  = NB * NSS;              // 200000 scan elements

    char* ws = (char*)d_ws;
    const size_t szH1b = (size_t)N * D1 * sizeof(unsigned short);
    unsigned short* h1b   = (unsigned short*)(ws);
    unsigned short* hmidb = (unsigned short*)(ws + szH1b);
    unsigned short* Wp1   = (unsigned short*)(ws + 2 * szH1b);
    unsigned short* Wp2   = Wp1 + 32768;
    float* al_s1 = (float*)(Wp2 + 32768);
    float* al_d1 = al_s1 + (size_t)N * H1;
    float* al_s2 = al_d1 + (size_t)N * H1;
    float* al_d2 = al_s2 + (size_t)N * H2;
    int* sdeg    = (int*)(al_d2 + (size_t)N * H2);   // M (stripe-major [s][b])
    int* bcur    = sdeg + M;                         // M (stripe-major)
    int* start   = bcur + M;                         // M ((b,s)-major, pristine)
    int* rowptr  = start + M;                        // N+1
    int* csr_src = rowptr + (N + 1);                 // E
    int* bsum    = csr_src + E;                      // scanBlocks (<=1024)
    unsigned int* pairs = (unsigned int*)(bsum + 1024);  // E
    unsigned short* h2b = h1b;   // reuse after agg1 consumed h1b

    const int edgeBlocks = (E + 255) / 256;
    const int scanBlocks = (M + 255) / 256;   // 782
    const int tileBlocks = (N + 15) / 16;

    conv_hist_kernel<<<256 + NSS, 256, 0, stream>>>(W1, W2, Wp1, Wp2, ei, E, sdeg, NB);
    scan_gemm1_kernel<<<scanBlocks + tileBlocks, 256, 0, stream>>>(
        sdeg, NB, M, bsum, scanBlocks, x, Wp1, as1, ad1, h1b, al_s1, al_d1, N);
    scan_final<<<scanBlocks, 256, 0, stream>>>(sdeg, bsum, M, NB, start, bcur);
    bucket_scatter<<<edgeBlocks, 256, 0, stream>>>(ei, E, NB, bcur, pairs);
    fill2_kernel<<<NB, 256, 0, stream>>>(pairs, start, N, NB, E, rowptr, csr_src);

    agg1_kernel<<<N, 64, 0, stream>>>(rowptr, csr_src, (const uint2*)h1b,
                                      al_s1, al_d1, b1, lnw, lnb,
                                      (uint2*)hmidb, N);
    gemm2_mfma<<<tileBlocks, 256, 0, stream>>>(hmidb, Wp2, as2, ad2, h2b, al_s2, al_d2, N);
    agg2_kernel<<<N, 64, 0, stream>>>(rowptr, csr_src, (const unsigned int*)h2b,
                                      al_s2, al_d2, b2, (float*)d_out, N);
}

// Round 14
// 278.930 us; speedup vs baseline: 1.0238x; 1.0238x over previous
//
#include <hip/hip_runtime.h>
#include <hip/hip_bf16.h>
#include <math.h>

#define IN_DIM  128
#define HID     64
#define H1      4
#define H2      2
#define OUT_DIM 64
#define D1      256   // H1*HID
#define D2      128   // H2*OUT_DIM
#define LRELU   0.2f
#define LN_EPS  1e-5f
#define BK      16    // nodes per fill bucket
#define NS      8     // stripes (= scatter blockIdx mod 8 -> XCD heuristic)
#define HKPS    49    // histogram blocks per stripe
#define MAXNB   4096  // LDS histogram capacity (NB=3125 here)

using short8 = __attribute__((ext_vector_type(8))) short;
using f32x4  = __attribute__((ext_vector_type(4))) float;

static __device__ __forceinline__ unsigned short f2bf_bits(float f)
{
    __hip_bfloat16 b = __float2bfloat16(f);
    return *reinterpret_cast<unsigned short*>(&b);
}
static __device__ __forceinline__ float2 unpack_bf2(unsigned int p)
{
    float2 r;
    r.x = __uint_as_float(p << 16);
    r.y = __uint_as_float(p & 0xffff0000u);
    return r;
}
static __device__ __forceinline__ unsigned int pack_bf2(float x, float y)
{
    return (unsigned int)f2bf_bits(x) | ((unsigned int)f2bf_bits(y) << 16);
}

static __device__ __forceinline__ float lrelu_exp(float v)
{
    v = v > 0.f ? v : LRELU * v;
    return __expf(v);
}

// inline int64-vs-int32 edge_index probe: int64 data has zero odd words.
static __device__ __forceinline__ int detect_i64(const int* __restrict__ ei)
{
    int any_odd_nonzero = 0;
    #pragma unroll
    for (int k = 1; k < 16; k += 2) any_odd_nonzero |= (ei[k] != 0);
    return any_odd_nonzero ? 0 : 1;
}

// ---------------- fused weight pre-pack + LDS-aggregated stripe histogram (R12) -------------
__global__ __launch_bounds__(256) void conv_hist_kernel(
    const float* __restrict__ W1, const float* __restrict__ W2,
    unsigned short* __restrict__ Wp1, unsigned short* __restrict__ Wp2,
    const int* __restrict__ ei, int E, int* __restrict__ sdeg, int NB)
{
    __shared__ int hist[MAXNB];
    const int bid = blockIdx.x;
    if (bid < 256) {
        int tid = bid * 256 + threadIdx.x;   // 0..65535
        if (tid < 32768) {                   // W1: 4 ksteps x 16 stripes
            int j = tid & 7, l = (tid >> 3) & 63, rest = tid >> 9;
            int s = rest & 15, t = rest >> 4;
            int k = t * 32 + (l >> 4) * 8 + j, col = s * 16 + (l & 15);
            Wp1[tid] = f2bf_bits(W1[k * D1 + col]);
        } else {                             // W2: 8 ksteps x 8 stripes
            int id = tid - 32768;
            int j = id & 7, l = (id >> 3) & 63, rest = id >> 9;
            int s = rest & 7, t = rest >> 3;
            int k = t * 32 + (l >> 4) * 8 + j, col = s * 16 + (l & 15);
            Wp2[id] = f2bf_bits(W2[k * D2 + col]);
        }
        return;
    }

    const int i64f = detect_i64(ei);
    const int h = bid - 256;
    const int s = h & 7, k = h >> 3;         // stripe, per-stripe block idx
    const int numGroups = (E + 255) >> 8;

    for (int i = threadIdx.x; i < NB; i += 256) hist[i] = 0;
    __syncthreads();

    for (int g = s + 8 * k; g < numGroups; g += 8 * HKPS) {
        int e = (g << 8) + threadIdx.x;
        if (e < E) {
            int dst = i64f ? ei[2 * ((size_t)E + e)] : ei[E + e];
            atomicAdd(&hist[dst >> 4], 1);   // BK=16 (LDS atomic)
        }
    }
    __syncthreads();
    for (int i = threadIdx.x; i < NB; i += 256) {
        int v = hist[i];
        if (v) atomicAdd(&sdeg[s * NB + i], v);
    }
}

// ---------------- fused scan_partial(sdeg, (b,s)-order) + MFMA GEMM1 (R12) ----------------
__global__ __launch_bounds__(256) void scan_gemm1_kernel(
    const int* __restrict__ sdeg, int NB, int M, int* __restrict__ bsum, int scanB,
    const float* __restrict__ x, const unsigned short* __restrict__ Wp,
    const float* __restrict__ att_s, const float* __restrict__ att_d,
    unsigned short* __restrict__ h1b,
    float* __restrict__ al_s, float* __restrict__ al_d, int N)
{
    __shared__ __align__(16) unsigned short As[16 * 136];  // K=128 pad->136
    const int tid = threadIdx.x;

    if ((int)blockIdx.x < scanB) {
        int* sh = (int*)As;   // reuse LDS
        int i = blockIdx.x * 256 + tid;
        int v = 0;
        if (i < M) v = sdeg[(i & 7) * NB + (i >> 3)];   // (b,s) lexicographic
        sh[tid] = v;
        __syncthreads();
        for (int st = 128; st > 0; st >>= 1) {
            if (tid < st) sh[tid] += sh[tid + st];
            __syncthreads();
        }
        if (tid == 0) bsum[blockIdx.x] = sh[0];
        return;
    }

    const int n0 = ((int)blockIdx.x - scanB) * 16;
    const int l = tid & 63, w = tid >> 6;

    #pragma unroll
    for (int it = 0; it < 2; ++it) {
        int ch = tid + it * 256;            // 512 chunks of 4 floats
        int r = ch >> 5, c4 = (ch & 31) * 4;
        int row = n0 + r;
        float4 v = (row < N) ? ((const float4*)x)[(size_t)row * 32 + (c4 >> 2)]
                             : make_float4(0.f, 0.f, 0.f, 0.f);
        ushort4 pk = make_ushort4(f2bf_bits(v.x), f2bf_bits(v.y),
                                  f2bf_bits(v.z), f2bf_bits(v.w));
        *(ushort4*)&As[r * 136 + c4] = pk;
    }

    short8 bfr[4][4];
    #pragma unroll
    for (int t = 0; t < 4; ++t)
        #pragma unroll
        for (int p = 0; p < 4; ++p)
            bfr[t][p] = ((const short8*)Wp)[(t * 16 + (w * 4 + p)) * 64 + l];

    __syncthreads();

    f32x4 acc[4] = {{0.f,0.f,0.f,0.f},{0.f,0.f,0.f,0.f},
                    {0.f,0.f,0.f,0.f},{0.f,0.f,0.f,0.f}};
    #pragma unroll
    for (int t = 0; t < 4; ++t) {
        short8 a = *(const short8*)&As[(l & 15) * 136 + t * 32 + (l >> 4) * 8];
        #pragma unroll
        for (int p = 0; p < 4; ++p)
            acc[p] = __builtin_amdgcn_mfma_f32_16x16x32_bf16(a, bfr[t][p], acc[p], 0, 0, 0);
    }

    const int colbase = w * 64 + (l & 15);
    const int rowbase = n0 + (l >> 4) * 4;
    #pragma unroll
    for (int p = 0; p < 4; ++p) {
        int col = colbase + p * 16;
        #pragma unroll
        for (int r = 0; r < 4; ++r) {
            int row = rowbase + r;
            if (row < N) h1b[(size_t)row * D1 + col] = f2bf_bits(acc[p][r]);
        }
    }

    float as_p[4], ad_p[4];
    #pragma unroll
    for (int p = 0; p < 4; ++p) {
        as_p[p] = att_s[colbase + p * 16];
        ad_p[p] = att_d[colbase + p * 16];
    }
    #pragma unroll
    for (int r = 0; r < 4; ++r) {
        float ps = acc[0][r] * as_p[0] + acc[1][r] * as_p[1]
                 + acc[2][r] * as_p[2] + acc[3][r] * as_p[3];
        float pd = acc[0][r] * ad_p[0] + acc[1][r] * ad_p[1]
                 + acc[2][r] * ad_p[2] + acc[3][r] * ad_p[3];
        #pragma unroll
        for (int off = 8; off > 0; off >>= 1) {
            ps += __shfl_down(ps, off);
            pd += __shfl_down(pd, off);
        }
        int row = rowbase + r;
        if ((l & 15) == 0 && row < N) {
            al_s[(size_t)row * H1 + w] = ps;
            al_d[(size_t)row * H1 + w] = pd;
        }
    }
}

// scan_final over M=NB*8 elements in (b,s) order (R12).
__global__ __launch_bounds__(256) void scan_final(
    const int* __restrict__ sdeg, const int* __restrict__ bsum, int B, int M, int NB,
    int* __restrict__ start, int* __restrict__ bcur)
{
    __shared__ int sb[256];
    __shared__ int s[256];
    sb[threadIdx.x] = (threadIdx.x < B) ? bsum[threadIdx.x] : 0;
    __syncthreads();
    for (int st = 1; st < 256; st <<= 1) {
        int t = (threadIdx.x >= st) ? sb[threadIdx.x - st] : 0;
        __syncthreads();
        sb[threadIdx.x] += t;
        __syncthreads();
    }
    const int blockOff = (blockIdx.x == 0) ? 0 : sb[blockIdx.x - 1];

    int i = blockIdx.x * 256 + threadIdx.x;
    int v = (i < M) ? sdeg[(i & 7) * NB + (i >> 3)] : 0;
    s[threadIdx.x] = v;
    __syncthreads();
    for (int st = 1; st < 256; st <<= 1) {
        int t = (threadIdx.x >= st) ? s[threadIdx.x - st] : 0;
        __syncthreads();
        s[threadIdx.x] += t;
        __syncthreads();
    }
    int excl = s[threadIdx.x] - v + blockOff;
    if (i < M) {
        start[i] = excl;
        bcur[(i & 7) * NB + (i >> 3)] = excl;
    }
}

// ---------------- scatter edges into (bucket,stripe) regions (R12) ----------------
__global__ __launch_bounds__(256) void bucket_scatter(
    const int* __restrict__ ei, int E, int NB,
    int* __restrict__ bcur, unsigned int* __restrict__ pairs)
{
    const int i64f = detect_i64(ei);
    int e = blockIdx.x * 256 + threadIdx.x;
    if (e >= E) return;
    int src, dst;
    if (i64f) { src = ei[2 * (size_t)e]; dst = ei[2 * ((size_t)E + e)]; }
    else      { src = ei[e];             dst = ei[E + e]; }
    int s = (e >> 8) & 7;
    int pos = atomicAdd(&bcur[s * NB + (dst >> 4)], 1);
    pairs[pos] = ((unsigned int)src << 16) | (unsigned int)dst;
}

// ---------------- agg1 body for one node (64 lanes), src indices via pointer ----------------
static __device__ __forceinline__ void agg1_node(
    int n, int l, const int* __restrict__ srcidx, int ec,
    const uint2* __restrict__ h1p,
    const float* __restrict__ al_s, const float* __restrict__ al_d,
    const float* __restrict__ b1,
    const float* __restrict__ ln_w, const float* __restrict__ ln_b,
    uint2* __restrict__ hmidp)
{
    const int h = l >> 4;
    const float ad = al_d[(size_t)n * H1 + h];

    float a0[4] = {0.f,0.f,0.f,0.f}, a1[4] = {0.f,0.f,0.f,0.f};
    float a2[4] = {0.f,0.f,0.f,0.f}, a3[4] = {0.f,0.f,0.f,0.f};
    float dn0, dn1 = 0.f, dn2 = 0.f, dn3 = 0.f;

    {   // self loop
        float w = lrelu_exp(al_s[(size_t)n * H1 + h] + ad);
        uint2 p = h1p[(size_t)n * 64 + l];
        float2 va = unpack_bf2(p.x), vb = unpack_bf2(p.y);
        a0[0] = w * va.x; a0[1] = w * va.y; a0[2] = w * vb.x; a0[3] = w * vb.y;
        dn0 = w;
    }

    int i = 0;
#define LOADI(k)  int s##k = srcidx[i + k];
#define LOADR(k)  uint2 p##k = h1p[(size_t)s##k * 64 + l]; \
                  float g##k = al_s[(size_t)s##k * H1 + h];
#define WACC(A, D, k) { float w = lrelu_exp(g##k + ad); \
                        float2 va = unpack_bf2(p##k.x), vb = unpack_bf2(p##k.y); \
                        A[0] += w * va.x; A[1] += w * va.y; \
                        A[2] += w * vb.x; A[3] += w * vb.y; D += w; }
    for (; i + 4 <= ec; i += 4) {
        LOADI(0) LOADI(1) LOADI(2) LOADI(3)
        LOADR(0) LOADR(1) LOADR(2) LOADR(3)
        WACC(a0, dn0, 0) WACC(a1, dn1, 1) WACC(a2, dn2, 2) WACC(a3, dn3, 3)
    }
    for (; i < ec; ++i) {
        LOADI(0) LOADR(0) WACC(a0, dn0, 0)
    }
#undef LOADI
#undef LOADR
#undef WACC

    const float inv = 1.f / ((dn0 + dn1) + (dn2 + dn3));
    float4 bb = ((const float4*)b1)[l];
    float v[4];
    v[0] = ((a0[0]+a1[0]) + (a2[0]+a3[0])) * inv + bb.x;
    v[1] = ((a0[1]+a1[1]) + (a2[1]+a3[1])) * inv + bb.y;
    v[2] = ((a0[2]+a1[2]) + (a2[2]+a3[2])) * inv + bb.z;
    v[3] = ((a0[3]+a1[3]) + (a2[3]+a3[3])) * inv + bb.w;

    // LayerNorm over 256 channels: single-wave shfl reduction
    float s  = (v[0]+v[1]) + (v[2]+v[3]);
    float s2 = (v[0]*v[0]+v[1]*v[1]) + (v[2]*v[2]+v[3]*v[3]);
    #pragma unroll
    for (int off = 32; off > 0; off >>= 1) {
        s  += __shfl_down(s,  off);
        s2 += __shfl_down(s2, off);
    }
    const float mu   = __shfl(s,  0) * (1.f / 256.f);
    const float ex2  = __shfl(s2, 0) * (1.f / 256.f);
    const float rstd = rsqrtf(ex2 - mu * mu + LN_EPS);
    float4 lw = ((const float4*)ln_w)[l];
    float4 lb = ((const float4*)ln_b)[l];
    float y0 = (v[0] - mu) * rstd * lw.x + lb.x;
    float y1 = (v[1] - mu) * rstd * lw.y + lb.y;
    float y2 = (v[2] - mu) * rstd * lw.z + lb.z;
    float y3 = (v[3] - mu) * rstd * lw.w + lb.w;
    y0 = y0 > 0.f ? y0 : (__expf(y0) - 1.f);
    y1 = y1 > 0.f ? y1 : (__expf(y1) - 1.f);
    y2 = y2 > 0.f ? y2 : (__expf(y2) - 1.f);
    y3 = y3 > 0.f ? y3 : (__expf(y3) - 1.f);
    uint2 outp;
    outp.x = pack_bf2(y0, y1);
    outp.y = pack_bf2(y2, y3);
    hmidp[(size_t)n * 64 + l] = outp;
}

// ---------------- fused fill + agg1: block = 16-node bucket, 256 threads ----------------
// Phase A: build the bucket's CSR segment in LDS (and write rowptr/csr_src for agg2).
// Phase B: 4 waves x 4 sequential nodes run agg1 with src indices read from LDS.
__global__ __launch_bounds__(256) void fill_agg1_kernel(
    const unsigned int* __restrict__ pairs, const int* __restrict__ start,
    const uint2* __restrict__ h1p,
    const float* __restrict__ al_s, const float* __restrict__ al_d,
    const float* __restrict__ b1,
    const float* __restrict__ ln_w, const float* __restrict__ ln_b,
    int N, int NB, int E,
    int* __restrict__ rowptr, int* __restrict__ csr_src,
    uint2* __restrict__ hmidp)
{
    __shared__ int cnt[BK], cur[BK], cur0[BK];
    __shared__ int stage[2048];
    const int b = blockIdx.x;
    const int t = threadIdx.x;
    const int base = start[b * NS];
    const int segend = (b + 1 < NB) ? start[(b + 1) * NS] : E;
    const int seglen = segend - base;
    const bool fits = (seglen <= 2048);

    if (t < BK) cnt[t] = 0;
    __syncthreads();
    for (int i = t; i < seglen; i += 256)
        atomicAdd(&cnt[pairs[base + i] & (BK - 1)], 1);
    __syncthreads();
    if (t == 0) {
        int run = 0;
        for (int j = 0; j < BK; ++j) {
            cur[j] = run; cur0[j] = run;
            int node = b * BK + j;
            if (node < N) rowptr[node] = base + run;
            run += cnt[j];
        }
        if (b == NB - 1) rowptr[N] = E;
    }
    __syncthreads();

    if (fits) {
        for (int i = t; i < seglen; i += 256) {
            unsigned int p = pairs[base + i];
            int pos = atomicAdd(&cur[p & (BK - 1)], 1);
            stage[pos] = (int)(p >> 16);
        }
        __syncthreads();
        for (int i = t; i < seglen; i += 256)
            csr_src[base + i] = stage[i];       // agg2 still reads from global
    } else {
        for (int i = t; i < seglen; i += 256) {
            unsigned int p = pairs[base + i];
            int pos = atomicAdd(&cur[p & (BK - 1)], 1);
            csr_src[base + pos] = (int)(p >> 16);
        }
    }
    __syncthreads();

    // Phase B: wave w handles nodes b*16 + w*4 + r, r = 0..3 (wave-uniform)
    const int l = t & 63, w = t >> 6;
    #pragma unroll
    for (int r = 0; r < 4; ++r) {
        int j = w * 4 + r;
        int n = b * BK + j;
        if (n >= N) break;
        const int* srcidx = fits ? ((const int*)stage + cur0[j])
                                 : (csr_src + base + cur0[j]);
        agg1_node(n, l, srcidx, cnt[j], h1p, al_s, al_d, b1, ln_w, ln_b, hmidp);
    }
}

// ---------------- MFMA GEMM2: h2b[N,128] = hmidb[N,256] @ W2 + fused logits ----------------
__global__ __launch_bounds__(256) void gemm2_mfma(
    const unsigned short* __restrict__ hmidb, const unsigned short* __restrict__ Wp,
    const float* __restrict__ att_s, const float* __restrict__ att_d,
    unsigned short* __restrict__ h2b,
    float* __restrict__ al_s, float* __restrict__ al_d, int N)
{
    __shared__ __align__(16) unsigned short As[16 * 264];  // K=256 pad->264
    __shared__ float psL[4][16], pdL[4][16];
    const int tid = threadIdx.x;
    const int n0 = blockIdx.x * 16;
    const int l = tid & 63, w = tid >> 6;

    const short8 zero8 = {0,0,0,0,0,0,0,0};
    #pragma unroll
    for (int it = 0; it < 2; ++it) {
        int ch = tid + it * 256;            // 512 chunks of 8 bf16
        int r = ch >> 5, c8 = (ch & 31) * 8;
        int row = n0 + r;
        short8 v = (row < N) ? ((const short8*)hmidb)[(size_t)row * 32 + (ch & 31)] : zero8;
        *(short8*)&As[r * 264 + c8] = v;
    }

    short8 bfr[8][2];
    #pragma unroll
    for (int t = 0; t < 8; ++t)
        #pragma unroll
        for (int q = 0; q < 2; ++q)
            bfr[t][q] = ((const short8*)Wp)[(t * 8 + (w * 2 + q)) * 64 + l];

    __syncthreads();

    f32x4 acc[2] = {{0.f,0.f,0.f,0.f},{0.f,0.f,0.f,0.f}};
    #pragma unroll
    for (int t = 0; t < 8; ++t) {
        short8 a = *(const short8*)&As[(l & 15) * 264 + t * 32 + (l >> 4) * 8];
        #pragma unroll
        for (int q = 0; q < 2; ++q)
            acc[q] = __builtin_amdgcn_mfma_f32_16x16x32_bf16(a, bfr[t][q], acc[q], 0, 0, 0);
    }

    const int colbase = w * 32 + (l & 15);
    const int rowbase = n0 + (l >> 4) * 4;
    #pragma unroll
    for (int q = 0; q < 2; ++q) {
        int col = colbase + q * 16;
        #pragma unroll
        for (int r = 0; r < 4; ++r) {
            int row = rowbase + r;
            if (row < N) h2b[(size_t)row * D2 + col] = f2bf_bits(acc[q][r]);
        }
    }

    float as_q[2], ad_q[2];
    #pragma unroll
    for (int q = 0; q < 2; ++q) {
        as_q[q] = att_s[colbase + q * 16];
        ad_q[q] = att_d[colbase + q * 16];
    }
    #pragma unroll
    for (int r = 0; r < 4; ++r) {
        float ps = acc[0][r] * as_q[0] + acc[1][r] * as_q[1];
        float pd = acc[0][r] * ad_q[0] + acc[1][r] * ad_q[1];
        #pragma unroll
        for (int off = 8; off > 0; off >>= 1) {
            ps += __shfl_down(ps, off);
            pd += __shfl_down(pd, off);
        }
        if ((l & 15) == 0) {
            psL[w][(l >> 4) * 4 + r] = ps;
            pdL[w][(l >> 4) * 4 + r] = pd;
        }
    }
    __syncthreads();
    if (tid < 32) {
        int rl = tid & 15, hh = tid >> 4;
        int row = n0 + rl;
        if (row < N) {
            al_s[(size_t)row * H2 + hh] = psL[2*hh][rl] + psL[2*hh+1][rl];
            al_d[(size_t)row * H2 + hh] = pdL[2*hh][rl] + pdL[2*hh+1][rl];
        }
    }
}

// ---------------- Layer-2 aggregation: 64 thr/node, 2 ch/lane, 4-wide + shfl head-mean ------
__global__ __launch_bounds__(64) void agg2_kernel(
    const int* __restrict__ rowptr, const int* __restrict__ csr_src,
    const unsigned int* __restrict__ h2p,   // [N,64] packed bf16x2
    const float* __restrict__ al_s, const float* __restrict__ al_d,
    const float* __restrict__ b2,
    float* __restrict__ out, int N)
{
    const int n = blockIdx.x;
    const int l = threadIdx.x;
    const int h = l >> 5;
    const float ad = al_d[(size_t)n * H2 + h];

    float ax0, ay0, dn0;
    float ax1 = 0.f, ay1 = 0.f, dn1 = 0.f;
    float ax2 = 0.f, ay2 = 0.f, dn2 = 0.f;
    float ax3 = 0.f, ay3 = 0.f, dn3 = 0.f;
    {
        float w = lrelu_exp(al_s[(size_t)n * H2 + h] + ad);
        float2 hv = unpack_bf2(h2p[(size_t)n * 64 + l]);
        ax0 = w * hv.x; ay0 = w * hv.y; dn0 = w;
    }

    const int beg = rowptr[n], end = rowptr[n + 1];
    int i = beg;

#define LOADI(k)  int s##k = csr_src[i + k];
#define LOADR(k)  unsigned int p##k = h2p[(size_t)s##k * 64 + l]; \
                  float g##k = al_s[(size_t)s##k * H2 + h];
#define WACC(AX, AY, D, k) { float w = lrelu_exp(g##k + ad); \
                             float2 vv = unpack_bf2(p##k); \
                             AX += w * vv.x; AY += w * vv.y; D += w; }

    for (; i + 4 <= end; i += 4) {
        LOADI(0) LOADI(1) LOADI(2) LOADI(3)
        LOADR(0) LOADR(1) LOADR(2) LOADR(3)
        WACC(ax0, ay0, dn0, 0) WACC(ax1, ay1, dn1, 1)
        WACC(ax2, ay2, dn2, 2) WACC(ax3, ay3, dn3, 3)
    }
    for (; i < end; ++i) {
        LOADI(0) LOADR(0) WACC(ax0, ay0, dn0, 0)
    }
#undef LOADI
#undef LOADR
#undef WACC

    const float inv = 1.f / ((dn0 + dn1) + (dn2 + dn3));
    const float vx = ((ax0 + ax1) + (ax2 + ax3)) * inv;
    const float vy = ((ay0 + ay1) + (ay2 + ay3)) * inv;

    // head mean via shfl: lane i<32 holds head0 ch {2i,2i+1}, lane 32+i head1.
    const float vx1 = __shfl(vx, l + 32);
    const float vy1 = __shfl(vy, l + 32);
    if (l < 32) {
        float2 bb = ((const float2*)b2)[l];
        float2 o;
        o.x = 0.5f * (vx + vx1) + bb.x;
        o.y = 0.5f * (vy + vy1) + bb.y;
        ((float2*)out)[(size_t)n * 32 + l] = o;
    }
}

extern "C" void kernel_launch(void* const* d_in, const int* in_sizes, int n_in,
                              void* d_out, int out_size, void* d_ws, size_t ws_size,
                              hipStream_t stream)
{
    const float* x   = (const float*)d_in[0];
    const int*   ei  = (const int*)d_in[1];
    const float* W1  = (const float*)d_in[2];
    const float* as1 = (const float*)d_in[3];
    const float* ad1 = (const float*)d_in[4];
    const float* b1  = (const float*)d_in[5];
    const float* lnw = (const float*)d_in[6];
    const float* lnb = (const float*)d_in[7];
    const float* W2  = (const float*)d_in[8];
    const float* as2 = (const float*)d_in[9];
    const float* ad2 = (const float*)d_in[10];
    const float* b2  = (const float*)d_in[11];

    const int N = in_sizes[0] / IN_DIM;   // 50000 (< 65536: uint16 packing valid)
    const int E = in_sizes[1] / 2;        // 800000
    const int NB = (N + BK - 1) / BK;     // 3125 buckets (<= MAXNB)
    const int M  = NB * NS;               // 25000 scan elements

    char* ws = (char*)d_ws;
    const size_t szH1b = (size_t)N * D1 * sizeof(unsigned short);
    unsigned short* h1b   = (unsigned short*)(ws);
    unsigned short* hmidb = (unsigned short*)(ws + szH1b);
    unsigned short* Wp1   = (unsigned short*)(ws + 2 * szH1b);
    unsigned short* Wp2   = Wp1 + 32768;
    float* al_s1 = (float*)(Wp2 + 32768);
    float* al_d1 = al_s1 + (size_t)N * H1;
    float* al_s2 = al_d1 + (size_t)N * H1;
    float* al_d2 = al_s2 + (size_t)N * H2;
    int* sdeg    = (int*)(al_d2 + (size_t)N * H2);   // M (stripe-major [s][b])
    int* bcur    = sdeg + M;                         // M (stripe-major)
    int* start   = bcur + M;                         // M ((b,s)-major, pristine)
    int* rowptr  = start + M;                        // N+1
    int* csr_src = rowptr + (N + 1);                 // E
    int* bsum    = csr_src + E;                      // 256
    unsigned int* pairs = (unsigned int*)(bsum + 256);  // E
    unsigned short* h2b = h1b;   // reuse after agg1 consumed h1b

    hipMemsetAsync(sdeg, 0, (size_t)M * sizeof(int), stream);

    const int edgeBlocks = (E + 255) / 256;
    const int scanBlocks = (M + 255) / 256;   // 98 <= 256
    const int tileBlocks = (N + 15) / 16;

    conv_hist_kernel<<<256 + NS * HKPS, 256, 0, stream>>>(W1, W2, Wp1, Wp2, ei, E, sdeg, NB);
    scan_gemm1_kernel<<<scanBlocks + tileBlocks, 256, 0, stream>>>(
        sdeg, NB, M, bsum, scanBlocks, x, Wp1, as1, ad1, h1b, al_s1, al_d1, N);
    scan_final<<<scanBlocks, 256, 0, stream>>>(sdeg, bsum, scanBlocks, M, NB, start, bcur);
    bucket_scatter<<<edgeBlocks, 256, 0, stream>>>(ei, E, NB, bcur, pairs);
    fill_agg1_kernel<<<NB, 256, 0, stream>>>(pairs, start, (const uint2*)h1b,
                                             al_s1, al_d1, b1, lnw, lnb,
                                             N, NB, E, rowptr, csr_src,
                                             (uint2*)hmidb);
    gemm2_mfma<<<tileBlocks, 256, 0, stream>>>(hmidb, Wp2, as2, ad2, h2b, al_s2, al_d2, N);
    agg2_kernel<<<N, 64, 0, stream>>>(rowptr, csr_src, (const unsigned int*)h2b,
                                      al_s2, al_d2, b2, (float*)d_out, N);
}

// Round 15
// 273.660 us; speedup vs baseline: 1.0435x; 1.0193x over previous
//
#include <hip/hip_runtime.h>
#include <hip/hip_bf16.h>
#include <math.h>

#define IN_DIM  128
#define HID     64
#define H1      4
#define H2      2
#define OUT_DIM 64
#define D1      256   // H1*HID
#define D2      128   // H2*OUT_DIM
#define LRELU   0.2f
#define LN_EPS  1e-5f
#define BK      16    // nodes per fill bucket
#define NS      8     // stripes (= scatter blockIdx mod 8 -> XCD heuristic)
#define HKPS    49    // histogram blocks per stripe
#define MAXNB   4096  // LDS histogram capacity (NB=3125 here)

using short8 = __attribute__((ext_vector_type(8))) short;
using f32x4  = __attribute__((ext_vector_type(4))) float;

static __device__ __forceinline__ unsigned short f2bf_bits(float f)
{
    __hip_bfloat16 b = __float2bfloat16(f);
    return *reinterpret_cast<unsigned short*>(&b);
}
static __device__ __forceinline__ float2 unpack_bf2(unsigned int p)
{
    float2 r;
    r.x = __uint_as_float(p << 16);
    r.y = __uint_as_float(p & 0xffff0000u);
    return r;
}
static __device__ __forceinline__ unsigned int pack_bf2(float x, float y)
{
    return (unsigned int)f2bf_bits(x) | ((unsigned int)f2bf_bits(y) << 16);
}

static __device__ __forceinline__ float lrelu_exp(float v)
{
    v = v > 0.f ? v : LRELU * v;
    return __expf(v);
}

// inline int64-vs-int32 edge_index probe: int64 data has zero odd words.
static __device__ __forceinline__ int detect_i64(const int* __restrict__ ei)
{
    int any_odd_nonzero = 0;
    #pragma unroll
    for (int k = 1; k < 16; k += 2) any_odd_nonzero |= (ei[k] != 0);
    return any_odd_nonzero ? 0 : 1;
}

// ---------------- fused weight pre-pack + PARTITIONED stripe histogram ----------------
// blocks [0,256): pack W1/W2. blocks [256,256+NS*HKPS): block (s,k) builds a
// private LDS histogram of 16-node buckets over its edge groups, then PLAIN
// STORES it to sdeg_part[(s*HKPS+k)*NB + b]. Zero global atomics, no memset.
__global__ __launch_bounds__(256) void conv_hist_kernel(
    const float* __restrict__ W1, const float* __restrict__ W2,
    unsigned short* __restrict__ Wp1, unsigned short* __restrict__ Wp2,
    const int* __restrict__ ei, int E, int* __restrict__ sdeg_part, int NB)
{
    __shared__ int hist[MAXNB];
    const int bid = blockIdx.x;
    if (bid < 256) {
        int tid = bid * 256 + threadIdx.x;   // 0..65535
        if (tid < 32768) {                   // W1: 4 ksteps x 16 stripes
            int j = tid & 7, l = (tid >> 3) & 63, rest = tid >> 9;
            int s = rest & 15, t = rest >> 4;
            int k = t * 32 + (l >> 4) * 8 + j, col = s * 16 + (l & 15);
            Wp1[tid] = f2bf_bits(W1[k * D1 + col]);
        } else {                             // W2: 8 ksteps x 8 stripes
            int id = tid - 32768;
            int j = id & 7, l = (id >> 3) & 63, rest = id >> 9;
            int s = rest & 7, t = rest >> 3;
            int k = t * 32 + (l >> 4) * 8 + j, col = s * 16 + (l & 15);
            Wp2[id] = f2bf_bits(W2[k * D2 + col]);
        }
        return;
    }

    const int i64f = detect_i64(ei);
    const int h = bid - 256;
    const int s = h & 7, k = h >> 3;         // stripe, per-stripe block idx
    const int numGroups = (E + 255) >> 8;

    for (int i = threadIdx.x; i < NB; i += 256) hist[i] = 0;
    __syncthreads();

    for (int g = s + 8 * k; g < numGroups; g += 8 * HKPS) {
        int e = (g << 8) + threadIdx.x;
        if (e < E) {
            int dst = i64f ? ei[2 * ((size_t)E + e)] : ei[E + e];
            atomicAdd(&hist[dst >> 4], 1);   // BK=16 (LDS atomic)
        }
    }
    __syncthreads();
    int* dst = sdeg_part + (size_t)(s * HKPS + k) * NB;
    for (int i = threadIdx.x; i < NB; i += 256)
        dst[i] = hist[i];                    // single owner: plain store
}

// ---------------- fused scan_partial(sum parts, (b,s)-order) + MFMA GEMM1 ----------------
__global__ __launch_bounds__(256) void scan_gemm1_kernel(
    const int* __restrict__ sdeg_part, int NB, int M,
    int* __restrict__ ssum, int* __restrict__ bsum, int scanB,
    const float* __restrict__ x, const unsigned short* __restrict__ Wp,
    const float* __restrict__ att_s, const float* __restrict__ att_d,
    unsigned short* __restrict__ h1b,
    float* __restrict__ al_s, float* __restrict__ al_d, int N)
{
    __shared__ __align__(16) unsigned short As[16 * 136];  // K=128 pad->136
    const int tid = threadIdx.x;

    if ((int)blockIdx.x < scanB) {
        int* sh = (int*)As;   // reuse LDS
        int i = blockIdx.x * 256 + tid;
        int v = 0;
        if (i < M) {
            int b = i >> 3, s = i & 7;      // (b,s) lexicographic
            const int* p = sdeg_part + (size_t)s * HKPS * NB + b;
            for (int k = 0; k < HKPS; ++k) v += p[(size_t)k * NB];
            ssum[i] = v;
        }
        sh[tid] = v;
        __syncthreads();
        for (int st = 128; st > 0; st >>= 1) {
            if (tid < st) sh[tid] += sh[tid + st];
            __syncthreads();
        }
        if (tid == 0) bsum[blockIdx.x] = sh[0];
        return;
    }

    const int n0 = ((int)blockIdx.x - scanB) * 16;
    const int l = tid & 63, w = tid >> 6;

    #pragma unroll
    for (int it = 0; it < 2; ++it) {
        int ch = tid + it * 256;            // 512 chunks of 4 floats
        int r = ch >> 5, c4 = (ch & 31) * 4;
        int row = n0 + r;
        float4 v = (row < N) ? ((const float4*)x)[(size_t)row * 32 + (c4 >> 2)]
                             : make_float4(0.f, 0.f, 0.f, 0.f);
        ushort4 pk = make_ushort4(f2bf_bits(v.x), f2bf_bits(v.y),
                                  f2bf_bits(v.z), f2bf_bits(v.w));
        *(ushort4*)&As[r * 136 + c4] = pk;
    }

    short8 bfr[4][4];
    #pragma unroll
    for (int t = 0; t < 4; ++t)
        #pragma unroll
        for (int p = 0; p < 4; ++p)
            bfr[t][p] = ((const short8*)Wp)[(t * 16 + (w * 4 + p)) * 64 + l];

    __syncthreads();

    f32x4 acc[4] = {{0.f,0.f,0.f,0.f},{0.f,0.f,0.f,0.f},
                    {0.f,0.f,0.f,0.f},{0.f,0.f,0.f,0.f}};
    #pragma unroll
    for (int t = 0; t < 4; ++t) {
        short8 a = *(const short8*)&As[(l & 15) * 136 + t * 32 + (l >> 4) * 8];
        #pragma unroll
        for (int p = 0; p < 4; ++p)
            acc[p] = __builtin_amdgcn_mfma_f32_16x16x32_bf16(a, bfr[t][p], acc[p], 0, 0, 0);
    }

    const int colbase = w * 64 + (l & 15);
    const int rowbase = n0 + (l >> 4) * 4;
    #pragma unroll
    for (int p = 0; p < 4; ++p) {
        int col = colbase + p * 16;
        #pragma unroll
        for (int r = 0; r < 4; ++r) {
            int row = rowbase + r;
            if (row < N) h1b[(size_t)row * D1 + col] = f2bf_bits(acc[p][r]);
        }
    }

    float as_p[4], ad_p[4];
    #pragma unroll
    for (int p = 0; p < 4; ++p) {
        as_p[p] = att_s[colbase + p * 16];
        ad_p[p] = att_d[colbase + p * 16];
    }
    #pragma unroll
    for (int r = 0; r < 4; ++r) {
        float ps = acc[0][r] * as_p[0] + acc[1][r] * as_p[1]
                 + acc[2][r] * as_p[2] + acc[3][r] * as_p[3];
        float pd = acc[0][r] * ad_p[0] + acc[1][r] * ad_p[1]
                 + acc[2][r] * ad_p[2] + acc[3][r] * ad_p[3];
        #pragma unroll
        for (int off = 8; off > 0; off >>= 1) {
            ps += __shfl_down(ps, off);
            pd += __shfl_down(pd, off);
        }
        int row = rowbase + r;
        if ((l & 15) == 0 && row < N) {
            al_s[(size_t)row * H1 + w] = ps;
            al_d[(size_t)row * H1 + w] = pd;
        }
    }
}

// scan_final over M=NB*8 elements in (b,s) order, reading pre-summed ssum.
__global__ __launch_bounds__(256) void scan_final(
    const int* __restrict__ ssum, const int* __restrict__ bsum, int B, int M, int NB,
    int* __restrict__ start, int* __restrict__ bcur)
{
    __shared__ int sb[256];
    __shared__ int s[256];
    sb[threadIdx.x] = (threadIdx.x < B) ? bsum[threadIdx.x] : 0;
    __syncthreads();
    for (int st = 1; st < 256; st <<= 1) {
        int t = (threadIdx.x >= st) ? sb[threadIdx.x - st] : 0;
        __syncthreads();
        sb[threadIdx.x] += t;
        __syncthreads();
    }
    const int blockOff = (blockIdx.x == 0) ? 0 : sb[blockIdx.x - 1];

    int i = blockIdx.x * 256 + threadIdx.x;
    int v = (i < M) ? ssum[i] : 0;
    s[threadIdx.x] = v;
    __syncthreads();
    for (int st = 1; st < 256; st <<= 1) {
        int t = (threadIdx.x >= st) ? s[threadIdx.x - st] : 0;
        __syncthreads();
        s[threadIdx.x] += t;
        __syncthreads();
    }
    int excl = s[threadIdx.x] - v + blockOff;
    if (i < M) {
        start[i] = excl;
        bcur[(i & 7) * NB + (i >> 3)] = excl;
    }
}

// ---------------- scatter edges into (bucket,stripe) regions (R12) ----------------
__global__ __launch_bounds__(256) void bucket_scatter(
    const int* __restrict__ ei, int E, int NB,
    int* __restrict__ bcur, unsigned int* __restrict__ pairs)
{
    const int i64f = detect_i64(ei);
    int e = blockIdx.x * 256 + threadIdx.x;
    if (e >= E) return;
    int src, dst;
    if (i64f) { src = ei[2 * (size_t)e]; dst = ei[2 * ((size_t)E + e)]; }
    else      { src = ei[e];             dst = ei[E + e]; }
    int s = (e >> 8) & 7;
    int pos = atomicAdd(&bcur[s * NB + (dst >> 4)], 1);
    pairs[pos] = ((unsigned int)src << 16) | (unsigned int)dst;
}

// ---------------- fill2: derive per-node offsets in LDS, write rowptr + csr (R12) ----------
__global__ __launch_bounds__(256) void fill2_kernel(
    const unsigned int* __restrict__ pairs, const int* __restrict__ start,
    int N, int NB, int E,
    int* __restrict__ rowptr, int* __restrict__ csr_src)
{
    __shared__ int cnt[BK], cur[BK];
    __shared__ int stage[2048];
    const int b = blockIdx.x;
    const int t = threadIdx.x;
    const int base = start[b * NS];
    const int segend = (b + 1 < NB) ? start[(b + 1) * NS] : E;
    const int seglen = segend - base;

    if (t < BK) cnt[t] = 0;
    __syncthreads();
    for (int i = t; i < seglen; i += 256)
        atomicAdd(&cnt[pairs[base + i] & (BK - 1)], 1);
    __syncthreads();
    if (t == 0) {
        int run = 0;
        for (int j = 0; j < BK; ++j) {
            cur[j] = run;
            int node = b * BK + j;
            if (node < N) rowptr[node] = base + run;
            run += cnt[j];
        }
        if (b == NB - 1) rowptr[N] = E;
    }
    __syncthreads();

    if (seglen <= 2048) {
        for (int i = t; i < seglen; i += 256) {
            unsigned int p = pairs[base + i];
            int pos = atomicAdd(&cur[p & (BK - 1)], 1);
            stage[pos] = (int)(p >> 16);
        }
        __syncthreads();
        for (int i = t; i < seglen; i += 256)
            csr_src[base + i] = stage[i];
    } else {
        for (int i = t; i < seglen; i += 256) {
            unsigned int p = pairs[base + i];
            int pos = atomicAdd(&cur[p & (BK - 1)], 1);
            csr_src[base + pos] = (int)(p >> 16);
        }
    }
}

// ---------------- MFMA GEMM2: h2b[N,128] = hmidb[N,256] @ W2 + fused logits ----------------
__global__ __launch_bounds__(256) void gemm2_mfma(
    const unsigned short* __restrict__ hmidb, const unsigned short* __restrict__ Wp,
    const float* __restrict__ att_s, const float* __restrict__ att_d,
    unsigned short* __restrict__ h2b,
    float* __restrict__ al_s, float* __restrict__ al_d, int N)
{
    __shared__ __align__(16) unsigned short As[16 * 264];  // K=256 pad->264
    __shared__ float psL[4][16], pdL[4][16];
    const int tid = threadIdx.x;
    const int n0 = blockIdx.x * 16;
    const int l = tid & 63, w = tid >> 6;

    const short8 zero8 = {0,0,0,0,0,0,0,0};
    #pragma unroll
    for (int it = 0; it < 2; ++it) {
        int ch = tid + it * 256;            // 512 chunks of 8 bf16
        int r = ch >> 5, c8 = (ch & 31) * 8;
        int row = n0 + r;
        short8 v = (row < N) ? ((const short8*)hmidb)[(size_t)row * 32 + (ch & 31)] : zero8;
        *(short8*)&As[r * 264 + c8] = v;
    }

    short8 bfr[8][2];
    #pragma unroll
    for (int t = 0; t < 8; ++t)
        #pragma unroll
        for (int q = 0; q < 2; ++q)
            bfr[t][q] = ((const short8*)Wp)[(t * 8 + (w * 2 + q)) * 64 + l];

    __syncthreads();

    f32x4 acc[2] = {{0.f,0.f,0.f,0.f},{0.f,0.f,0.f,0.f}};
    #pragma unroll
    for (int t = 0; t < 8; ++t) {
        short8 a = *(const short8*)&As[(l & 15) * 264 + t * 32 + (l >> 4) * 8];
        #pragma unroll
        for (int q = 0; q < 2; ++q)
            acc[q] = __builtin_amdgcn_mfma_f32_16x16x32_bf16(a, bfr[t][q], acc[q], 0, 0, 0);
    }

    const int colbase = w * 32 + (l & 15);
    const int rowbase = n0 + (l >> 4) * 4;
    #pragma unroll
    for (int q = 0; q < 2; ++q) {
        int col = colbase + q * 16;
        #pragma unroll
        for (int r = 0; r < 4; ++r) {
            int row = rowbase + r;
            if (row < N) h2b[(size_t)row * D2 + col] = f2bf_bits(acc[q][r]);
        }
    }

    float as_q[2], ad_q[2];
    #pragma unroll
    for (int q = 0; q < 2; ++q) {
        as_q[q] = att_s[colbase + q * 16];
        ad_q[q] = att_d[colbase + q * 16];
    }
    #pragma unroll
    for (int r = 0; r < 4; ++r) {
        float ps = acc[0][r] * as_q[0] + acc[1][r] * as_q[1];
        float pd = acc[0][r] * ad_q[0] + acc[1][r] * ad_q[1];
        #pragma unroll
        for (int off = 8; off > 0; off >>= 1) {
            ps += __shfl_down(ps, off);
            pd += __shfl_down(pd, off);
        }
        if ((l & 15) == 0) {
            psL[w][(l >> 4) * 4 + r] = ps;
            pdL[w][(l >> 4) * 4 + r] = pd;
        }
    }
    __syncthreads();
    if (tid < 32) {
        int rl = tid & 15, hh = tid >> 4;
        int row = n0 + rl;
        if (row < N) {
            al_s[(size_t)row * H2 + hh] = psL[2*hh][rl] + psL[2*hh+1][rl];
            al_d[(size_t)row * H2 + hh] = pdL[2*hh][rl] + pdL[2*hh+1][rl];
        }
    }
}

// ---------------- Layer-1 aggregation: 64 thr/node, 4 ch/lane, 4-wide, loads-first (R12) ----
__global__ __launch_bounds__(64) void agg1_kernel(
    const int* __restrict__ rowptr, const int* __restrict__ csr_src,
    const uint2* __restrict__ h1p,   // [N,64] packed bf16x4
    const float* __restrict__ al_s, const float* __restrict__ al_d,
    const float* __restrict__ b1,
    const float* __restrict__ ln_w, const float* __restrict__ ln_b,
    uint2* __restrict__ hmidp, int N)  // [N,64] packed bf16x4 out
{
    const int n = blockIdx.x;
    const int l = threadIdx.x;
    const int h = l >> 4;
    const float ad = al_d[(size_t)n * H1 + h];

    float a0[4] = {0.f,0.f,0.f,0.f}, a1[4] = {0.f,0.f,0.f,0.f};
    float a2[4] = {0.f,0.f,0.f,0.f}, a3[4] = {0.f,0.f,0.f,0.f};
    float dn0, dn1 = 0.f, dn2 = 0.f, dn3 = 0.f;

    {   // self loop
        float w = lrelu_exp(al_s[(size_t)n * H1 + h] + ad);
        uint2 p = h1p[(size_t)n * 64 + l];
        float2 va = unpack_bf2(p.x), vb = unpack_bf2(p.y);
        a0[0] = w * va.x; a0[1] = w * va.y; a0[2] = w * vb.x; a0[3] = w * vb.y;
        dn0 = w;
    }

    const int beg = rowptr[n], end = rowptr[n + 1];
    int i = beg;

#define LOADI(k)  int s##k = csr_src[i + k];
#define LOADR(k)  uint2 p##k = h1p[(size_t)s##k * 64 + l]; \
                  float g##k = al_s[(size_t)s##k * H1 + h];
#define WACC(A, D, k) { float w = lrelu_exp(g##k + ad); \
                        float2 va = unpack_bf2(p##k.x), vb = unpack_bf2(p##k.y); \
                        A[0] += w * va.x; A[1] += w * va.y; \
                        A[2] += w * vb.x; A[3] += w * vb.y; D += w; }

    for (; i + 4 <= end; i += 4) {
        LOADI(0) LOADI(1) LOADI(2) LOADI(3)
        LOADR(0) LOADR(1) LOADR(2) LOADR(3)
        WACC(a0, dn0, 0) WACC(a1, dn1, 1) WACC(a2, dn2, 2) WACC(a3, dn3, 3)
    }
    for (; i < end; ++i) {
        LOADI(0) LOADR(0) WACC(a0, dn0, 0)
    }
#undef LOADI
#undef LOADR
#undef WACC

    const float inv = 1.f / ((dn0 + dn1) + (dn2 + dn3));
    float4 bb = ((const float4*)b1)[l];
    float v[4];
    v[0] = ((a0[0]+a1[0]) + (a2[0]+a3[0])) * inv + bb.x;
    v[1] = ((a0[1]+a1[1]) + (a2[1]+a3[1])) * inv + bb.y;
    v[2] = ((a0[2]+a1[2]) + (a2[2]+a3[2])) * inv + bb.z;
    v[3] = ((a0[3]+a1[3]) + (a2[3]+a3[3])) * inv + bb.w;

    // LayerNorm over 256 channels: single-wave shfl reduction
    float s  = (v[0]+v[1]) + (v[2]+v[3]);
    float s2 = (v[0]*v[0]+v[1]*v[1]) + (v[2]*v[2]+v[3]*v[3]);
    #pragma unroll
    for (int off = 32; off > 0; off >>= 1) {
        s  += __shfl_down(s,  off);
        s2 += __shfl_down(s2, off);
    }
    const float mu   = __shfl(s,  0) * (1.f / 256.f);
    const float ex2  = __shfl(s2, 0) * (1.f / 256.f);
    const float rstd = rsqrtf(ex2 - mu * mu + LN_EPS);
    float4 lw = ((const float4*)ln_w)[l];
    float4 lb = ((const float4*)ln_b)[l];
    float y0 = (v[0] - mu) * rstd * lw.x + lb.x;
    float y1 = (v[1] - mu) * rstd * lw.y + lb.y;
    float y2 = (v[2] - mu) * rstd * lw.z + lb.z;
    float y3 = (v[3] - mu) * rstd * lw.w + lb.w;
    y0 = y0 > 0.f ? y0 : (__expf(y0) - 1.f);
    y1 = y1 > 0.f ? y1 : (__expf(y1) - 1.f);
    y2 = y2 > 0.f ? y2 : (__expf(y2) - 1.f);
    y3 = y3 > 0.f ? y3 : (__expf(y3) - 1.f);
    uint2 outp;
    outp.x = pack_bf2(y0, y1);
    outp.y = pack_bf2(y2, y3);
    hmidp[(size_t)n * 64 + l] = outp;
}

// ---------------- Layer-2 aggregation: 64 thr/node, 2 ch/lane, 4-wide + shfl head-mean ------
__global__ __launch_bounds__(64) void agg2_kernel(
    const int* __restrict__ rowptr, const int* __restrict__ csr_src,
    const unsigned int* __restrict__ h2p,   // [N,64] packed bf16x2
    const float* __restrict__ al_s, const float* __restrict__ al_d,
    const float* __restrict__ b2,
    float* __restrict__ out, int N)
{
    const int n = blockIdx.x;
    const int l = threadIdx.x;
    const int h = l >> 5;
    const float ad = al_d[(size_t)n * H2 + h];

    float ax0, ay0, dn0;
    float ax1 = 0.f, ay1 = 0.f, dn1 = 0.f;
    float ax2 = 0.f, ay2 = 0.f, dn2 = 0.f;
    float ax3 = 0.f, ay3 = 0.f, dn3 = 0.f;
    {
        float w = lrelu_exp(al_s[(size_t)n * H2 + h] + ad);
        float2 hv = unpack_bf2(h2p[(size_t)n * 64 + l]);
        ax0 = w * hv.x; ay0 = w * hv.y; dn0 = w;
    }

    const int beg = rowptr[n], end = rowptr[n + 1];
    int i = beg;

#define LOADI(k)  int s##k = csr_src[i + k];
#define LOADR(k)  unsigned int p##k = h2p[(size_t)s##k * 64 + l]; \
                  float g##k = al_s[(size_t)s##k * H2 + h];
#define WACC(AX, AY, D, k) { float w = lrelu_exp(g##k + ad); \
                             float2 vv = unpack_bf2(p##k); \
                             AX += w * vv.x; AY += w * vv.y; D += w; }

    for (; i + 4 <= end; i += 4) {
        LOADI(0) LOADI(1) LOADI(2) LOADI(3)
        LOADR(0) LOADR(1) LOADR(2) LOADR(3)
        WACC(ax0, ay0, dn0, 0) WACC(ax1, ay1, dn1, 1)
        WACC(ax2, ay2, dn2, 2) WACC(ax3, ay3, dn3, 3)
    }
    for (; i < end; ++i) {
        LOADI(0) LOADR(0) WACC(ax0, ay0, dn0, 0)
    }
#undef LOADI
#undef LOADR
#undef WACC

    const float inv = 1.f / ((dn0 + dn1) + (dn2 + dn3));
    const float vx = ((ax0 + ax1) + (ax2 + ax3)) * inv;
    const float vy = ((ay0 + ay1) + (ay2 + ay3)) * inv;

    // head mean via shfl: lane i<32 holds head0 ch {2i,2i+1}, lane 32+i head1.
    const float vx1 = __shfl(vx, l + 32);
    const float vy1 = __shfl(vy, l + 32);
    if (l < 32) {
        float2 bb = ((const float2*)b2)[l];
        float2 o;
        o.x = 0.5f * (vx + vx1) + bb.x;
        o.y = 0.5f * (vy + vy1) + bb.y;
        ((float2*)out)[(size_t)n * 32 + l] = o;
    }
}

extern "C" void kernel_launch(void* const* d_in, const int* in_sizes, int n_in,
                              void* d_out, int out_size, void* d_ws, size_t ws_size,
                              hipStream_t stream)
{
    const float* x   = (const float*)d_in[0];
    const int*   ei  = (const int*)d_in[1];
    const float* W1  = (const float*)d_in[2];
    const float* as1 = (const float*)d_in[3];
    const float* ad1 = (const float*)d_in[4];
    const float* b1  = (const float*)d_in[5];
    const float* lnw = (const float*)d_in[6];
    const float* lnb = (const float*)d_in[7];
    const float* W2  = (const float*)d_in[8];
    const float* as2 = (const float*)d_in[9];
    const float* ad2 = (const float*)d_in[10];
    const float* b2  = (const float*)d_in[11];

    const int N = in_sizes[0] / IN_DIM;   // 50000 (< 65536: uint16 packing valid)
    const int E = in_sizes[1] / 2;        // 800000
    const int NB = (N + BK - 1) / BK;     // 3125 buckets (<= MAXNB)
    const int M  = NB * NS;               // 25000 scan elements

    char* ws = (char*)d_ws;
    const size_t szH1b = (size_t)N * D1 * sizeof(unsigned short);
    unsigned short* h1b   = (unsigned short*)(ws);
    unsigned short* hmidb = (unsigned short*)(ws + szH1b);
    unsigned short* Wp1   = (unsigned short*)(ws + 2 * szH1b);
    unsigned short* Wp2   = Wp1 + 32768;
    float* al_s1 = (float*)(Wp2 + 32768);
    float* al_d1 = al_s1 + (size_t)N * H1;
    float* al_s2 = al_d1 + (size_t)N * H1;
    float* al_d2 = al_s2 + (size_t)N * H2;
    int* sdeg_part = (int*)(al_d2 + (size_t)N * H2);  // NS*HKPS*NB (no init needed)
    int* ssum    = sdeg_part + (size_t)NS * HKPS * NB; // M
    int* bcur    = ssum + M;                           // M (stripe-major)
    int* start   = bcur + M;                           // M ((b,s)-major, pristine)
    int* rowptr  = start + M;                          // N+1
    int* csr_src = rowptr + (N + 1);                   // E
    int* bsum    = csr_src + E;                        // 256
    unsigned int* pairs = (unsigned int*)(bsum + 256); // E
    unsigned short* h2b = h1b;   // reuse after agg1 consumed h1b

    const int edgeBlocks = (E + 255) / 256;
    const int scanBlocks = (M + 255) / 256;   // 98 <= 256
    const int tileBlocks = (N + 15) / 16;

    conv_hist_kernel<<<256 + NS * HKPS, 256, 0, stream>>>(W1, W2, Wp1, Wp2, ei, E,
                                                          sdeg_part, NB);
    scan_gemm1_kernel<<<scanBlocks + tileBlocks, 256, 0, stream>>>(
        sdeg_part, NB, M, ssum, bsum, scanBlocks, x, Wp1, as1, ad1, h1b, al_s1, al_d1, N);
    scan_final<<<scanBlocks, 256, 0, stream>>>(ssum, bsum, scanBlocks, M, NB, start, bcur);
    bucket_scatter<<<edgeBlocks, 256, 0, stream>>>(ei, E, NB, bcur, pairs);
    fill2_kernel<<<NB, 256, 0, stream>>>(pairs, start, N, NB, E, rowptr, csr_src);

    agg1_kernel<<<N, 64, 0, stream>>>(rowptr, csr_src, (const uint2*)h1b,
                                      al_s1, al_d1, b1, lnw, lnb,
                                      (uint2*)hmidb, N);
    gemm2_mfma<<<tileBlocks, 256, 0, stream>>>(hmidb, Wp2, as2, ad2, h2b, al_s2, al_d2, N);
    agg2_kernel<<<N, 64, 0, stream>>>(rowptr, csr_src, (const unsigned int*)h2b,
                                      al_s2, al_d2, b2, (float*)d_out, N);
}